// Round 1
// baseline (212.339 us; speedup 1.0000x reference)
//
#include <hip/hip_runtime.h>

typedef unsigned short u16;
typedef short bf16x8 __attribute__((ext_vector_type(8)));
typedef float f32x4 __attribute__((ext_vector_type(4)));

#define HID 768
#define NH  12
#define HD  64
#define BB  16
#define SEQ 512
#define TOK (BB*SEQ)   // 8192 tokens

static __device__ __forceinline__ u16 f2bf(float f){
  union { float f; unsigned u; } x; x.f = f;
  unsigned r = x.u + 0x7fffu + ((x.u >> 16) & 1u);   // RNE
  return (u16)(r >> 16);
}

static __device__ __forceinline__ void gl_lds16(const void* g, void* l){
  __builtin_amdgcn_global_load_lds(
      (const __attribute__((address_space(1))) unsigned int*)g,
      (__attribute__((address_space(3))) unsigned int*)l, 16, 0, 0);
}

// ---------------------------------------------------------------- convert ---
// segments: x -> bf16 | [Wq;Wk;Wv] -> bf16 | Wo -> bf16 | spatial+edge -> f32
__global__ __launch_bounds__(256, 4) void k_convert(
    const float* __restrict__ x,  const float* __restrict__ sp,
    const float* __restrict__ ed, const float* __restrict__ wq,
    const float* __restrict__ wk, const float* __restrict__ wv,
    const float* __restrict__ wo,
    u16* __restrict__ xbf, u16* __restrict__ wqkv, u16* __restrict__ wob,
    float* __restrict__ bsum)
{
  const int NQX = TOK*HID/4;        // 1,572,864
  const int NQW = 3*HID*HID/4;      //   442,368
  const int NQO = HID*HID/4;        //   147,456
  int idx = blockIdx.x*256 + threadIdx.x;
  if (idx < NQX){
    int e = idx*4;
    float4 v = *(const float4*)(x+e);
    ushort4 o; o.x=f2bf(v.x); o.y=f2bf(v.y); o.z=f2bf(v.z); o.w=f2bf(v.w);
    *(ushort4*)(xbf+e) = o;
  } else if (idx < NQX+NQW){
    int e = (idx-NQX)*4;
    int row = e/HID, col = e%HID;
    const float* w = (row<768) ? (wq+row*HID)
                   : (row<1536 ? wk+(row-768)*HID : wv+(row-1536)*HID);
    float4 v = *(const float4*)(w+col);
    ushort4 o; o.x=f2bf(v.x); o.y=f2bf(v.y); o.z=f2bf(v.z); o.w=f2bf(v.w);
    *(ushort4*)(wqkv+e) = o;
  } else if (idx < NQX+NQW+NQO){
    int e = (idx-NQX-NQW)*4;
    float4 v = *(const float4*)(wo+e);
    ushort4 o; o.x=f2bf(v.x); o.y=f2bf(v.y); o.z=f2bf(v.z); o.w=f2bf(v.w);
    *(ushort4*)(wob+e) = o;
  } else {
    int e = (idx-NQX-NQW-NQO)*4;
    float4 a = *(const float4*)(sp+e);
    float4 b = *(const float4*)(ed+e);
    float4 o; o.x=a.x+b.x; o.y=a.y+b.y; o.z=a.z+b.z; o.w=a.w+b.w;
    *(float4*)(bsum+e) = o;
  }
}

// ------------------------------------------------------------------- gemm ---
// C[M][N] = A[M][768] * Bt[N][768]^T. 128x128 tile, BK=32, 4 waves (2x2),
// wave tile 64x64 (4x4 frags of 16x16x32). m97-style global_load_lds staging.
// MODE 0: QKV epilogue (scatter to per-head Q/K/V^T, bv add). MODE 1: fp32+bo.
template<int MODE>
__global__ __launch_bounds__(256, 2) void k_gemm(
    const u16* __restrict__ A, const u16* __restrict__ Bt,
    const float* __restrict__ bias,
    u16* __restrict__ qh, u16* __restrict__ kh, u16* __restrict__ vth,
    float* __restrict__ outf)
{
  __shared__ u16 As[128*32];
  __shared__ u16 Bs[128*32];
  const int tid = threadIdx.x;
  const int wid = tid >> 6, lane = tid & 63;
  const int g = lane >> 4, c = lane & 15;
  const int wr = wid >> 1, wc = wid & 1;
  const long mbase = (long)blockIdx.y * 128;
  const int  nbase = blockIdx.x * 128;

  f32x4 acc[4][4];
  #pragma unroll
  for (int i=0;i<4;i++)
    #pragma unroll
    for (int j=0;j<4;j++){ f32x4 z = {0.f,0.f,0.f,0.f}; acc[i][j] = z; }

  const char* Abase = (const char*)A  + mbase * HID * 2;
  const char* Bbase = (const char*)Bt + (long)nbase * HID * 2;

  for (int kk = 0; kk < HID; kk += 32){
    #pragma unroll
    for (int ci = 0; ci < 2; ci++){
      int L = ci*4096 + wid*1024 + lane*16;   // byte in 8KB tile
      int row = L >> 6, inrow = L & 63;       // 64B per row of 32 bf16
      gl_lds16(Abase + (long)row*1536 + kk*2 + inrow,
               (char*)As + ci*4096 + wid*1024);
      gl_lds16(Bbase + (long)row*1536 + kk*2 + inrow,
               (char*)Bs + ci*4096 + wid*1024);
    }
    __syncthreads();   // drains vmcnt: staged tiles visible
    bf16x8 af[4], bfr[4];
    #pragma unroll
    for (int mt=0; mt<4; mt++){
      int row = wr*64 + mt*16 + c;
      af[mt] = *(const bf16x8*)((const char*)As + row*64 + g*16);
    }
    #pragma unroll
    for (int nt=0; nt<4; nt++){
      int row = wc*64 + nt*16 + c;
      bfr[nt] = *(const bf16x8*)((const char*)Bs + row*64 + g*16);
    }
    #pragma unroll
    for (int mt=0; mt<4; mt++)
      #pragma unroll
      for (int nt=0; nt<4; nt++)
        acc[mt][nt] = __builtin_amdgcn_mfma_f32_16x16x32_bf16(
            af[mt], bfr[nt], acc[mt][nt], 0,0,0);
    __syncthreads();   // before next stage overwrites
  }

  if constexpr (MODE == 1){
    #pragma unroll
    for (int nt=0; nt<4; nt++){
      int colg = nbase + wc*64 + nt*16 + c;
      float bb = bias[colg];
      #pragma unroll
      for (int mt=0; mt<4; mt++)
        #pragma unroll
        for (int r=0;r<4;r++){
          long rowg = mbase + wr*64 + mt*16 + g*4 + r;
          outf[rowg*HID + colg] = acc[mt][nt][r] + bb;
        }
    }
  } else {
    int region = blockIdx.x / 6;   // 18 col-tiles: 0-5 Q, 6-11 K, 12-17 V
    #pragma unroll
    for (int nt=0; nt<4; nt++){
      int colg = nbase + wc*64 + nt*16 + c;
      int o = colg - region*768;
      int h = o >> 6, dd = o & 63;
      float bb = (region==2) ? bias[o] : 0.f;
      #pragma unroll
      for (int mt=0; mt<4; mt++)
        #pragma unroll
        for (int r=0;r<4;r++){
          long rowg = mbase + wr*64 + mt*16 + g*4 + r;
          int b = (int)(rowg >> 9), n = (int)(rowg & 511);
          long hb = (long)(b*NH + h);
          u16 val = f2bf(acc[mt][nt][r] + bb);
          if (region==0)      qh[(hb*SEQ + n)*HD + dd] = val;
          else if (region==1) kh[(hb*SEQ + n)*HD + dd] = val;
          else                vth[(hb*HD + dd)*SEQ + n] = val;
        }
    }
  }
}

// ------------------------------------------------------------------- attn ---
// One block per (b, h, 64 q-rows); 4 waves x 16 rows. Full 512-col score row
// in registers (32 x f32x4/lane). K/V frags direct from global (L2-resident).
// P -> LDS (XOR-swizzled, per-wave 16KB) to relayout into MFMA A-frags.
__global__ __launch_bounds__(256, 2) void k_attn(
    const u16* __restrict__ Qh, const u16* __restrict__ Kh,
    const u16* __restrict__ VTh, const float* __restrict__ bsum,
    u16* __restrict__ attn)
{
  __shared__ u16 Pl[4*8192];   // 64 KB: per-wave 16x512 bf16, swizzled
  const int tid = threadIdx.x;
  const int wid = tid>>6, lane = tid&63, g = lane>>4, c = lane&15;
  const int bid = blockIdx.x;
  const int qt = bid & 7, h = (bid>>3) % 12, b = bid/96;
  const u16* Qp = Qh  + (long)(b*NH+h)*SEQ*HD;
  const u16* Kp = Kh  + (long)(b*NH+h)*SEQ*HD;
  const u16* Vp = VTh + (long)(b*NH+h)*HD*SEQ;
  const int qbase = qt*64 + wid*16;

  bf16x8 aq[2];
  #pragma unroll
  for (int j=0;j<2;j++)
    aq[j] = *(const bf16x8*)(Qp + (qbase + c)*HD + j*32 + g*8);

  f32x4 s[32];
  #pragma unroll
  for (int T=0;T<32;T++){ f32x4 z = {0.f,0.f,0.f,0.f}; s[T]=z; }

  // QK^T: A=Q rows (m=c), B=K rows (n=c), k-dim = d
  #pragma unroll
  for (int T=0;T<32;T++){
    bf16x8 b0 = *(const bf16x8*)(Kp + (T*16 + c)*HD +  0 + g*8);
    bf16x8 b1 = *(const bf16x8*)(Kp + (T*16 + c)*HD + 32 + g*8);
    s[T] = __builtin_amdgcn_mfma_f32_16x16x32_bf16(aq[0], b0, s[T], 0,0,0);
    s[T] = __builtin_amdgcn_mfma_f32_16x16x32_bf16(aq[1], b1, s[T], 0,0,0);
  }

  const float scale = 0.036084391824351615f;   // 768^-0.5 (HIDDEN, not head)
  const float* bp = bsum + (long)b*SEQ*SEQ;
  float m[4] = {-1e30f,-1e30f,-1e30f,-1e30f};
  int   nz[4] = {0,0,0,0};
  #pragma unroll
  for (int T=0;T<32;T++){
    int col = T*16 + c;
    #pragma unroll
    for (int r=0;r<4;r++){
      int q = qbase + g*4 + r;
      float v = s[T][r]*scale + bp[(long)q*SEQ + col];
      s[T][r] = v;
      nz[r] |= (v != 0.f) ? 1 : 0;
      m[r] = fmaxf(m[r], v);
    }
  }
  #pragma unroll
  for (int r=0;r<4;r++)
    #pragma unroll
    for (int mk=1; mk<16; mk<<=1){
      m[r]  = fmaxf(m[r], __shfl_xor(m[r], mk, 64));
      nz[r] |= __shfl_xor(nz[r], mk, 64);
    }
  float l[4] = {0.f,0.f,0.f,0.f};
  #pragma unroll
  for (int T=0;T<32;T++)
    #pragma unroll
    for (int r=0;r<4;r++){
      float p = nz[r] ? __expf(s[T][r] - m[r]) : 0.f;   // zero-row -> p=0
      s[T][r] = p;
      l[r] += p;
    }
  #pragma unroll
  for (int r=0;r<4;r++){
    #pragma unroll
    for (int mk=1; mk<16; mk<<=1) l[r] += __shfl_xor(l[r], mk, 64);
    if (!nz[r]) l[r] = 1.f;   // avoid 0/0; outputs are 0 anyway
  }

  // P -> LDS bf16, swizzle byte ^= ((row&7)<<4) (G4 fix for 1KB row stride)
  u16* Pw = Pl + wid*8192;
  #pragma unroll
  for (int T=0;T<32;T++)
    #pragma unroll
    for (int r=0;r<4;r++){
      int rowl = g*4 + r;
      int byte = rowl*1024 + (T*16 + c)*2;
      int phys = byte ^ ((rowl&7)<<4);
      *(u16*)((char*)Pw + phys) = f2bf(s[T][r]);
    }
  __syncthreads();

  // PV: A = P (m=c, k contiguous from LDS), B = V^T rows (n=d=c, k contiguous)
  f32x4 o[4];
  #pragma unroll
  for (int dt=0;dt<4;dt++){ f32x4 z = {0.f,0.f,0.f,0.f}; o[dt]=z; }
  #pragma unroll
  for (int ck=0; ck<4; ck++)
    #pragma unroll
    for (int ks=0; ks<4; ks++){
      int byte = c*1024 + ck*256 + ks*64 + g*16;
      int phys = byte ^ ((c&7)<<4);
      bf16x8 pa = *(const bf16x8*)((const char*)Pw + phys);
      #pragma unroll
      for (int dt=0; dt<4; dt++){
        bf16x8 vb = *(const bf16x8*)(Vp + (dt*16 + c)*SEQ + ck*128 + ks*32 + g*8);
        o[dt] = __builtin_amdgcn_mfma_f32_16x16x32_bf16(pa, vb, o[dt], 0,0,0);
      }
    }

  #pragma unroll
  for (int dt=0; dt<4; dt++){
    int colg = h*64 + dt*16 + c;
    #pragma unroll
    for (int r=0;r<4;r++){
      int q = qbase + g*4 + r;
      float val = o[dt][r] / l[r];
      attn[(long)(b*SEQ + q)*HID + colg] = f2bf(val);
    }
  }
}

// ----------------------------------------------------------------- launch ---
extern "C" void kernel_launch(void* const* d_in, const int* in_sizes, int n_in,
                              void* d_out, int out_size, void* d_ws, size_t ws_size,
                              hipStream_t stream)
{
  const float* x  = (const float*)d_in[0];
  const float* sp = (const float*)d_in[1];
  const float* ed = (const float*)d_in[2];
  const float* Wq = (const float*)d_in[3];
  const float* Wk = (const float*)d_in[4];
  const float* Wv = (const float*)d_in[5];
  const float* bv = (const float*)d_in[6];
  const float* Wo = (const float*)d_in[7];
  const float* bo = (const float*)d_in[8];
  float* out = (float*)d_out;

  u16* w = (u16*)d_ws;
  u16* xbf  = w;                      // 6,291,456 u16
  u16* wqkv = xbf  + TOK*HID;         // 1,769,472
  u16* wob  = wqkv + 3*HID*HID;       //   589,824
  u16* qh   = wob  + HID*HID;         // 6,291,456
  u16* kh   = qh   + TOK*HID;
  u16* vth  = kh   + TOK*HID;
  u16* attn = vth  + TOK*HID;
  float* bsum = (float*)(attn + TOK*HID);   // 4,194,304 f32 -> total ~84.4 MB

  k_convert<<<12544, 256, 0, stream>>>(x, sp, ed, Wq, Wk, Wv, Wo,
                                       xbf, wqkv, wob, bsum);
  dim3 g1(18, 64);
  k_gemm<0><<<g1, 256, 0, stream>>>(xbf, wqkv, bv, qh, kh, vth, nullptr);
  k_attn<<<1536, 256, 0, stream>>>(qh, kh, vth, bsum, attn);
  dim3 g2(6, 64);
  k_gemm<1><<<g2, 256, 0, stream>>>(attn, wob, bo, nullptr, nullptr, nullptr, out);
}